// Round 4
// baseline (342.379 us; speedup 1.0000x reference)
//
#include <hip/hip_runtime.h>

// MemoryAugmentation: value[b,c] = softmax_m(x[b,c] . mem[m]) . mem
// B*C = 8192 rows, row length H*W = 7744 (= 1936 float4), M = 10 slots.
// One block of 256 threads handles R=4 consecutive rows.
//
// R4 changes vs R3 (88.45us, VGPR stuck at 64, BW 4.3/6.3 TB/s):
//  - __launch_bounds__(256,2): allow up to 256 VGPR so all loads can be live.
//  - explicit software pipeline: x loads (HBM latency) double-buffered one
//    full iteration ahead; mem loads (L2-resident) issued before the FMA
//    block each iteration. 7 full unrolled iterations + predicated tail
//    (1936 = 7*256 + 144) so ping-pong buffers get static register names.
//  - phase 2: mem loads double-buffered the same way; nt stores kept.

#define RROWS   4
#define NM      10
#define NVEC    1936          // 7744 / 4 float4 per row
#define THREADS 256
#define NFULL   7             // NVEC / THREADS
#define TAIL    144           // NVEC % THREADS

typedef float f32x4 __attribute__((ext_vector_type(4)));

__global__ __launch_bounds__(THREADS, 2)
void memaug_kernel(const float* __restrict__ x,
                   const float* __restrict__ mem,
                   float* __restrict__ out)
{
    const int tid = threadIdx.x;
    const long r0 = (long)blockIdx.x * RROWS;   // first row of this block

    const f32x4* __restrict__ m4 = (const f32x4*)mem;
    const f32x4* __restrict__ xr = (const f32x4*)x + r0 * NVEC;
    f32x4* __restrict__ orow     = (f32x4*)out + r0 * NVEC;

    // ---------------- Phase 1: scores[j][m] = x_row_j . mem_m ----------------
    float acc[RROWS][NM];
#pragma unroll
    for (int j = 0; j < RROWS; ++j)
#pragma unroll
        for (int m = 0; m < NM; ++m) acc[j][m] = 0.f;

    {
        f32x4 xa[RROWS], xb[RROWS], mv[NM];
        int iv = tid;
#pragma unroll
        for (int j = 0; j < RROWS; ++j) xa[j] = xr[j * NVEC + iv];

#pragma unroll
        for (int k = 0; k < NFULL; ++k) {
            const int ivn = iv + THREADS;
            // prefetch next x tile (full iteration of latency slack)
            if (k < NFULL - 1) {
#pragma unroll
                for (int j = 0; j < RROWS; ++j) xb[j] = xr[j * NVEC + ivn];
            } else {
                if (tid < TAIL) {
#pragma unroll
                    for (int j = 0; j < RROWS; ++j) xb[j] = xr[j * NVEC + ivn];
                }
            }
            // mem loads (L2-resident) for current iteration
#pragma unroll
            for (int m = 0; m < NM; ++m) mv[m] = m4[m * NVEC + iv];
#pragma unroll
            for (int m = 0; m < NM; ++m)
#pragma unroll
                for (int j = 0; j < RROWS; ++j)
                    acc[j][m] += xa[j].x * mv[m].x + xa[j].y * mv[m].y
                               + xa[j].z * mv[m].z + xa[j].w * mv[m].w;
#pragma unroll
            for (int j = 0; j < RROWS; ++j) xa[j] = xb[j];
            iv = ivn;
        }
        // tail (lanes tid < TAIL hold valid xa)
        if (tid < TAIL) {
#pragma unroll
            for (int m = 0; m < NM; ++m) mv[m] = m4[m * NVEC + iv];
#pragma unroll
            for (int m = 0; m < NM; ++m)
#pragma unroll
                for (int j = 0; j < RROWS; ++j)
                    acc[j][m] += xa[j].x * mv[m].x + xa[j].y * mv[m].y
                               + xa[j].z * mv[m].z + xa[j].w * mv[m].w;
        }
    }

    // ---------------- Wave reduce + softmax ----------------
#pragma unroll
    for (int j = 0; j < RROWS; ++j)
#pragma unroll
        for (int m = 0; m < NM; ++m) {
            float v = acc[j][m];
#pragma unroll
            for (int off = 32; off > 0; off >>= 1)
                v += __shfl_xor(v, off, 64);
            acc[j][m] = v;
        }

    __shared__ float red[4][RROWS][NM];
    __shared__ float prob[RROWS][NM];

    const int wave = tid >> 6;
    const int lane = tid & 63;
    if (lane == 0) {
#pragma unroll
        for (int j = 0; j < RROWS; ++j)
#pragma unroll
            for (int m = 0; m < NM; ++m) red[wave][j][m] = acc[j][m];
    }
    __syncthreads();

    if (tid < RROWS) {
        const int j = tid;
        float s[NM];
        float mx = -1e30f;
#pragma unroll
        for (int m = 0; m < NM; ++m) {
            s[m] = red[0][j][m] + red[1][j][m] + red[2][j][m] + red[3][j][m];
            mx = fmaxf(mx, s[m]);
        }
        float sum = 0.f;
#pragma unroll
        for (int m = 0; m < NM; ++m) { s[m] = expf(s[m] - mx); sum += s[m]; }
        const float inv = 1.f / sum;
#pragma unroll
        for (int m = 0; m < NM; ++m) prob[j][m] = s[m] * inv;
    }
    __syncthreads();

    float p[RROWS][NM];
#pragma unroll
    for (int j = 0; j < RROWS; ++j)
#pragma unroll
        for (int m = 0; m < NM; ++m) p[j][m] = prob[j][m];

    // ---------------- Phase 2: out_row_j = sum_m p[j][m] * mem_m ----------------
    {
        f32x4 ma[NM], mb[NM];
        int iv = tid;
#pragma unroll
        for (int m = 0; m < NM; ++m) ma[m] = m4[m * NVEC + iv];

#pragma unroll
        for (int k = 0; k < NFULL; ++k) {
            const int ivn = iv + THREADS;
            if (k < NFULL - 1) {
#pragma unroll
                for (int m = 0; m < NM; ++m) mb[m] = m4[m * NVEC + ivn];
            } else {
                if (tid < TAIL) {
#pragma unroll
                    for (int m = 0; m < NM; ++m) mb[m] = m4[m * NVEC + ivn];
                }
            }
            f32x4 ov[RROWS];
#pragma unroll
            for (int j = 0; j < RROWS; ++j) {
                ov[j] = ma[0] * p[j][0];
#pragma unroll
                for (int m = 1; m < NM; ++m) ov[j] += ma[m] * p[j][m];
            }
#pragma unroll
            for (int j = 0; j < RROWS; ++j)
                __builtin_nontemporal_store(ov[j], &orow[j * NVEC + iv]);
#pragma unroll
            for (int m = 0; m < NM; ++m) ma[m] = mb[m];
            iv = ivn;
        }
        if (tid < TAIL) {
            f32x4 ov[RROWS];
#pragma unroll
            for (int j = 0; j < RROWS; ++j) {
                ov[j] = ma[0] * p[j][0];
#pragma unroll
                for (int m = 1; m < NM; ++m) ov[j] += ma[m] * p[j][m];
            }
#pragma unroll
            for (int j = 0; j < RROWS; ++j)
                __builtin_nontemporal_store(ov[j], &orow[j * NVEC + iv]);
        }
    }
}

extern "C" void kernel_launch(void* const* d_in, const int* in_sizes, int n_in,
                              void* d_out, int out_size, void* d_ws, size_t ws_size,
                              hipStream_t stream) {
    const float* x   = (const float*)d_in[0];   // [32,256,88,88] f32
    const float* mem = (const float*)d_in[1];   // [10,88,88] f32
    float* out       = (float*)d_out;           // [32,256,88,88] f32

    const int rows   = 32 * 256;                // 8192
    const int blocks = rows / RROWS;            // 2048

    memaug_kernel<<<blocks, THREADS, 0, stream>>>(x, mem, out);
}

// Round 5
// 95.892 us; speedup vs baseline: 3.5705x; 3.5705x over previous
//
#include <hip/hip_runtime.h>

// MemoryAugmentation: value[b,c] = softmax_m(x[b,c] . mem[m]) . mem
// B*C = 8192 rows, row length H*W = 7744 (= 1936 float4), M = 10 slots.
// One block of 256 threads handles R=4 consecutive rows.
//
// R5 = R3 structure (88.45us) with ONE change: __launch_bounds__(256,2).
// R3's VGPR=64 serialized the 14-load batch (56 regs payload + 40 acc can't
// be live in 64 regs). R4's explicit double-buffer needed >128 regs and
// spilled to scratch (WRITE_SIZE 764MB = 3x output). The R3 shape needs
// ~110-120 regs -> fits 128 cap with no explicit pipelining.

#define RROWS   4
#define NM      10
#define NVEC    1936          // 7744 / 4 float4 per row
#define THREADS 256

typedef float f32x4 __attribute__((ext_vector_type(4)));

__global__ __launch_bounds__(THREADS, 2)
void memaug_kernel(const float* __restrict__ x,
                   const float* __restrict__ mem,
                   float* __restrict__ out)
{
    const int tid = threadIdx.x;
    const long r0 = (long)blockIdx.x * RROWS;   // first row of this block

    const f32x4* __restrict__ m4  = (const f32x4*)mem;
    const f32x4* __restrict__ xr  = (const f32x4*)x + r0 * NVEC;
    f32x4* __restrict__ orow      = (f32x4*)out + r0 * NVEC;

    // ---------------- Phase 1: scores[j][m] = x_row_j . mem_m ----------------
    float acc[RROWS][NM];
#pragma unroll
    for (int j = 0; j < RROWS; ++j)
#pragma unroll
        for (int m = 0; m < NM; ++m) acc[j][m] = 0.f;

    for (int iv = tid; iv < NVEC; iv += THREADS) {
        // issue ALL loads first so they are concurrently outstanding
        f32x4 xv[RROWS];
#pragma unroll
        for (int j = 0; j < RROWS; ++j)
            xv[j] = xr[j * NVEC + iv];
        f32x4 mv[NM];
#pragma unroll
        for (int m = 0; m < NM; ++m)
            mv[m] = m4[m * NVEC + iv];
#pragma unroll
        for (int m = 0; m < NM; ++m) {
#pragma unroll
            for (int j = 0; j < RROWS; ++j) {
                acc[j][m] += xv[j].x * mv[m].x + xv[j].y * mv[m].y
                           + xv[j].z * mv[m].z + xv[j].w * mv[m].w;
            }
        }
    }

    // Wave-level butterfly reduce (64 lanes)
#pragma unroll
    for (int j = 0; j < RROWS; ++j)
#pragma unroll
        for (int m = 0; m < NM; ++m) {
            float v = acc[j][m];
#pragma unroll
            for (int off = 32; off > 0; off >>= 1)
                v += __shfl_xor(v, off, 64);
            acc[j][m] = v;
        }

    __shared__ float red[4][RROWS][NM];   // per-wave partials
    __shared__ float prob[RROWS][NM];     // softmax probabilities

    const int wave = tid >> 6;
    const int lane = tid & 63;
    if (lane == 0) {
#pragma unroll
        for (int j = 0; j < RROWS; ++j)
#pragma unroll
            for (int m = 0; m < NM; ++m) red[wave][j][m] = acc[j][m];
    }
    __syncthreads();

    // ---------------- Softmax over m (threads 0..RROWS-1) ----------------
    if (tid < RROWS) {
        const int j = tid;
        float s[NM];
        float mx = -1e30f;
#pragma unroll
        for (int m = 0; m < NM; ++m) {
            s[m] = red[0][j][m] + red[1][j][m] + red[2][j][m] + red[3][j][m];
            mx = fmaxf(mx, s[m]);
        }
        float sum = 0.f;
#pragma unroll
        for (int m = 0; m < NM; ++m) { s[m] = expf(s[m] - mx); sum += s[m]; }
        const float inv = 1.f / sum;
#pragma unroll
        for (int m = 0; m < NM; ++m) prob[j][m] = s[m] * inv;
    }
    __syncthreads();

    float p[RROWS][NM];
#pragma unroll
    for (int j = 0; j < RROWS; ++j)
#pragma unroll
        for (int m = 0; m < NM; ++m) p[j][m] = prob[j][m];

    // ---------------- Phase 2: out_row_j = sum_m p[j][m] * mem_m ----------------
    for (int iv = tid; iv < NVEC; iv += THREADS) {
        f32x4 mv[NM];
#pragma unroll
        for (int m = 0; m < NM; ++m)
            mv[m] = m4[m * NVEC + iv];

        f32x4 ov[RROWS];
#pragma unroll
        for (int j = 0; j < RROWS; ++j) {
            ov[j] = mv[0] * p[j][0];
#pragma unroll
            for (int m = 1; m < NM; ++m) ov[j] += mv[m] * p[j][m];
        }
#pragma unroll
        for (int j = 0; j < RROWS; ++j)
            __builtin_nontemporal_store(ov[j], &orow[j * NVEC + iv]);
    }
}

extern "C" void kernel_launch(void* const* d_in, const int* in_sizes, int n_in,
                              void* d_out, int out_size, void* d_ws, size_t ws_size,
                              hipStream_t stream) {
    const float* x   = (const float*)d_in[0];   // [32,256,88,88] f32
    const float* mem = (const float*)d_in[1];   // [10,88,88] f32
    float* out       = (float*)d_out;           // [32,256,88,88] f32

    const int rows   = 32 * 256;                // 8192
    const int blocks = rows / RROWS;            // 2048

    memaug_kernel<<<blocks, THREADS, 0, stream>>>(x, mem, out);
}